// Round 5
// baseline (1125.325 us; speedup 1.0000x reference)
//
#include <hip/hip_runtime.h>
#include <hip/hip_bf16.h>

// Problem dims
constexpr int kS = 512;
constexpr int kB = 64;
constexpr int kE = 300;
constexpr int kH = 256;
constexpr int kM = 512;
constexpr int kC = 20;

typedef short s16x8 __attribute__((ext_vector_type(8)));
typedef float f32x4 __attribute__((ext_vector_type(4)));
typedef unsigned short u16x4 __attribute__((ext_vector_type(4)));
typedef _Float16 f16x8 __attribute__((ext_vector_type(8)));

__device__ __forceinline__ float fast_tanh(float z) {
    z = fminf(15.f, fmaxf(-15.f, z));
    float e = __expf(2.f * z);
    return 1.f - 2.f / (e + 1.f);
}

__device__ __forceinline__ unsigned short f2bf(float f) {
    __hip_bfloat16 h = __float2bfloat16(f);
    return *(unsigned short*)&h;
}
__device__ __forceinline__ float bf2f(unsigned short u) {
    __hip_bfloat16 h = *(__hip_bfloat16*)&u;
    return __bfloat162float(h);
}
union F16U { _Float16 h; unsigned short u; };
__device__ __forceinline__ unsigned short f16bits(_Float16 h) { F16U x; x.h = h; return x.u; }
__device__ __forceinline__ _Float16 bits2f16(unsigned short u) { F16U x; x.u = u; return x.h; }

// ---------------------------------------------------------------------------
// cat layout, per row (row = b*512 + s), 832 bf16 cols:
//   [0,256)   : proj writes X_l pre-acts; scan dir0 reads x / overwrites c_ls
//   [256,556) : emb (gather)
//   [556,576) : zeros (gather; proj A K-pad) -> scan dir1 overwrites with c_rs
//   [556,812) : c_rs after scan dir1
//   [576,832) : proj writes X_r pre-acts (col 576+h); scan dir1 reads them
//   [812,832) : X_r residue after scan; killed by Wmax zero cols
// ---------------------------------------------------------------------------

// K0a: weights -> bf16 (GEMMs) and f16 (scan W), zero-padded.
__global__ __launch_bounds__(256) void prepw_kernel(
    const float* __restrict__ max_w,
    const float* __restrict__ wsl, const float* __restrict__ wsr,
    const float* __restrict__ wl, const float* __restrict__ wr,
    unsigned short* __restrict__ Wmax, unsigned short* __restrict__ Wproj,
    unsigned short* __restrict__ Wscan)
{
    int idx = blockIdx.x * 256 + threadIdx.x;
    if (idx < 512 * 832) {
        int r = idx / 832, c = idx - r * 832;
        Wmax[idx] = f2bf(c < 812 ? max_w[r * 812 + c] : 0.f);
    }
    if (idx < 512 * 320) {
        int r = idx / 320, c = idx - r * 320;
        float v = 0.f;
        if (c < 300) v = (r < 256) ? wsl[r * 300 + c] : wsr[(r - 256) * 300 + c];
        Wproj[idx] = f2bf(v);
    }
    if (idx < 2 * 256 * 256) {
        int d = idx >> 16, rc = idx & 65535;
        float v = (d ? wr : wl)[rc];
        Wscan[idx] = f16bits((_Float16)v);
    }
}

// K0b: gather emb rows into cat cols [256,556); zero [556,576) and [812,832).
__global__ __launch_bounds__(128) void gather_kernel(
    const int* __restrict__ inp, const float* __restrict__ emb_table,
    unsigned short* __restrict__ cat)
{
    const int row = blockIdx.x;          // b*512 + s
    const int b = row >> 9, s = row & 511;
    const int t = threadIdx.x;
    unsigned short* dst = cat + (size_t)row * 832;
    const int v = inp[s * kB + b];
    const float* src = emb_table + (size_t)v * kE;
    if (t < 75) {
        float4 f = *(const float4*)&src[t * 4];
        u16x4 o = { f2bf(f.x), f2bf(f.y), f2bf(f.z), f2bf(f.w) };
        *(u16x4*)&dst[256 + t * 4] = o;
    } else if (t < 80) {
        u16x4 z = { 0, 0, 0, 0 };
        *(u16x4*)&dst[556 + (t - 75) * 4] = z;
    } else if (t < 85) {
        u16x4 z = { 0, 0, 0, 0 };
        *(u16x4*)&dst[812 + (t - 80) * 4] = z;
    }
}

// K1: proj GEMM (MFMA bf16), in-place epilogue into cat. (unchanged, passing)
__global__ __launch_bounds__(256) void proj_mfma_kernel(
    unsigned short* cat,
    const unsigned short* __restrict__ Wproj,
    const float* __restrict__ b_sl, const float* __restrict__ b_sr)
{
    __shared__ unsigned short As[128 * 40];
    __shared__ unsigned short Bs[128 * 40];
    const int tid = threadIdx.x;
    const int row0 = blockIdx.x * 128;
    const int col0 = blockIdx.y * 128;
    const int lane = tid & 63;
    const int wave = tid >> 6;
    const int wr = (wave >> 1) * 64, wc = (wave & 1) * 64;
    const int l15 = lane & 15, lk = (lane >> 4) * 8;
    const int srow = tid >> 1;
    const int sh = (tid & 1) * 16;

    const unsigned short* Ag = cat + (size_t)(row0 + srow) * 832 + 256 + sh;
    const unsigned short* Bg = Wproj + (size_t)(col0 + srow) * 320 + sh;

    f32x4 acc[4][4] = {};
    float4 av0 = *(const float4*)Ag;
    float4 av1 = *(const float4*)(Ag + 8);
    float4 bv0 = *(const float4*)Bg;
    float4 bv1 = *(const float4*)(Bg + 8);

    for (int kk = 0; kk < 10; ++kk) {
        __syncthreads();
        *(float4*)&As[srow * 40 + sh] = av0;
        *(float4*)&As[srow * 40 + sh + 8] = av1;
        *(float4*)&Bs[srow * 40 + sh] = bv0;
        *(float4*)&Bs[srow * 40 + sh + 8] = bv1;
        __syncthreads();
        if (kk < 9) {
            av0 = *(const float4*)(Ag + (kk + 1) * 32);
            av1 = *(const float4*)(Ag + (kk + 1) * 32 + 8);
            bv0 = *(const float4*)(Bg + (kk + 1) * 32);
            bv1 = *(const float4*)(Bg + (kk + 1) * 32 + 8);
        }
        s16x8 af[4], bf[4];
#pragma unroll
        for (int f = 0; f < 4; ++f) {
            af[f] = *(const s16x8*)&As[(wr + f * 16 + l15) * 40 + lk];
            bf[f] = *(const s16x8*)&Bs[(wc + f * 16 + l15) * 40 + lk];
        }
#pragma unroll
        for (int i = 0; i < 4; ++i)
#pragma unroll
            for (int j = 0; j < 4; ++j)
                acc[i][j] = __builtin_amdgcn_mfma_f32_16x16x32_bf16(af[i], bf[j], acc[i][j], 0, 0, 0);
    }

    const int rbase = row0 + wr + (lane >> 4) * 4;
#pragma unroll
    for (int j = 0; j < 4; ++j) {
        const int col = col0 + wc + j * 16 + l15;
        const float bias = (col < kH) ? b_sl[col] : b_sr[col - kH];
        const int ccol = (col < kH) ? col : (320 + col);
#pragma unroll
        for (int i = 0; i < 4; ++i) {
#pragma unroll
            for (int r = 0; r < 4; ++r) {
                const int row = rbase + i * 16 + r;
                cat[(size_t)row * 832 + ccol] = f2bf(acc[i][j][r] + bias);
            }
        }
    }
}

// ---------------------------------------------------------------------------
// K2: MFMA scan. 8 blocks = (dir 2) x (batch-group 4 of 16). 256 threads
// (4 waves); wave owns 64 output cols. Per step: C_next[16][256] =
// tanh(C @ W^T + bias + x) via split-f16 c (hi+lo, 2 MFMA passes) with W in
// 128 VGPRs. c exchanged via double-buffered XOR-swizzled LDS; 1 barrier/step.
// x prefetched 1 step ahead; acc initialized with bias + x.
// ---------------------------------------------------------------------------
__global__ __launch_bounds__(256) void scan_mfma_kernel(
    const float* __restrict__ c_l0, const float* __restrict__ c_r0,
    const float* __restrict__ b_l, const float* __restrict__ b_r,
    const unsigned short* __restrict__ Wscan,   // [2][256][256] f16
    unsigned short* cat)
{
    __shared__ unsigned short hiB[2][16 * 256];
    __shared__ unsigned short loB[2][16 * 256];

    const int dir = blockIdx.x >> 2;
    const int bg  = blockIdx.x & 3;
    const int tid = threadIdx.x;
    const int lane = tid & 63;
    const int wave = tid >> 6;
    const int l15 = lane & 15;
    const int q4  = lane >> 4;           // 0..3
    const int lk  = q4 * 8;
    const int n0  = wave * 64;

    const int xoff = dir ? 576 : 0;
    const int coff = dir ? 556 : 0;
    const float* bias = dir ? b_r : b_l;
    const float* c0v  = dir ? c_r0 : c_l0;
    const unsigned short* W = Wscan + (dir << 16);

    // B-fragments: W rows n0+j*16+l15, k = ks*32+lk (8 contiguous f16)
    f16x8 wf[4][8];
#pragma unroll
    for (int j = 0; j < 4; ++j)
#pragma unroll
        for (int ks = 0; ks < 8; ++ks)
            wf[j][ks] = *(const f16x8*)&W[(n0 + j * 16 + l15) * 256 + ks * 32 + lk];

    float biasv[4];
#pragma unroll
    for (int j = 0; j < 4; ++j) biasv[j] = bias[n0 + j * 16 + l15];

    // per-r row base pointers (batch = bg*16 + q4*4 + r)
    const unsigned short* xbase[4];
    unsigned short* cbase[4];
#pragma unroll
    for (int r = 0; r < 4; ++r) {
        size_t rowb = (size_t)(bg * 16 + q4 * 4 + r) * 512 * 832;
        xbase[r] = cat + rowb + xoff + n0 + l15;
        cbase[r] = cat + rowb + coff + n0 + l15;
    }

    // init c0 split into buf 0 (thread = col, all 16 rows)
    {
        float v = c0v[tid];
        _Float16 hf = (_Float16)v;
        float hff = (float)hf;
        _Float16 lf = (_Float16)(v - hff);
        unsigned short hb = f16bits(hf), lb = f16bits(lf);
        for (int row = 0; row < 16; ++row) {
            int idx = (row * 256 + tid) ^ ((row & 7) << 3);
            hiB[0][idx] = hb;
            loB[0][idx] = lb;
        }
    }

    int s = dir ? (kS - 1) : 0;
    unsigned short xc[4][4];
#pragma unroll
    for (int j = 0; j < 4; ++j)
#pragma unroll
        for (int r = 0; r < 4; ++r)
            xc[j][r] = xbase[r][(size_t)s * 832 + j * 16];

    // precomputed swizzled A-frag read offsets
    int ridx[8];
#pragma unroll
    for (int ks = 0; ks < 8; ++ks)
        ridx[ks] = (l15 * 256 + ks * 32 + lk) ^ ((l15 & 7) << 3);

    __syncthreads();

    for (int step = 0; step < kS; ++step) {
        const int p = step & 1;
        const int sn = (step < kS - 1) ? (dir ? (s - 1) : (s + 1)) : s;

        f32x4 acc[4];
#pragma unroll
        for (int j = 0; j < 4; ++j)
#pragma unroll
            for (int r = 0; r < 4; ++r)
                acc[j][r] = biasv[j] + bf2f(xc[j][r]);

        // prefetch next x
        unsigned short xn[4][4];
#pragma unroll
        for (int j = 0; j < 4; ++j)
#pragma unroll
            for (int r = 0; r < 4; ++r)
                xn[j][r] = xbase[r][(size_t)sn * 832 + j * 16];

#pragma unroll
        for (int ks = 0; ks < 8; ++ks) {
            f16x8 ah = *(const f16x8*)&hiB[p][ridx[ks]];
            f16x8 al = *(const f16x8*)&loB[p][ridx[ks]];
#pragma unroll
            for (int j = 0; j < 4; ++j) {
                acc[j] = __builtin_amdgcn_mfma_f32_16x16x32_f16(ah, wf[j][ks], acc[j], 0, 0, 0);
                acc[j] = __builtin_amdgcn_mfma_f32_16x16x32_f16(al, wf[j][ks], acc[j], 0, 0, 0);
            }
        }

        // epilogue: tanh, store c (bf16) to cat, split-f16 into buf p^1
#pragma unroll
        for (int j = 0; j < 4; ++j) {
#pragma unroll
            for (int r = 0; r < 4; ++r) {
                float z = acc[j][r];
                float e = __expf(2.f * z);
                float cg = 1.f - 2.f / (e + 1.f);
                cbase[r][(size_t)s * 832 + j * 16] = f2bf(cg);
                _Float16 hf = (_Float16)cg;
                float hff = (float)hf;
                _Float16 lf = (_Float16)(cg - hff);
                const int row = q4 * 4 + r;
                const int col = n0 + j * 16 + l15;
                const int widx = (row * 256 + col) ^ ((row & 7) << 3);
                hiB[p ^ 1][widx] = f16bits(hf);
                loB[p ^ 1][widx] = f16bits(lf);
            }
        }
#pragma unroll
        for (int j = 0; j < 4; ++j)
#pragma unroll
            for (int r = 0; r < 4; ++r)
                xc[j][r] = xn[j][r];
        s = sn;
        __syncthreads();
    }
}

// K3: maxlayer GEMM (MFMA bf16) + per-column max. (unchanged, passing)
__global__ __launch_bounds__(256) void maxlayer_mfma_kernel(
    const unsigned short* __restrict__ cat,
    const unsigned short* __restrict__ Wmax,
    float* __restrict__ part_max)
{
    __shared__ unsigned short As[128 * 40];
    __shared__ unsigned short Bs[128 * 40];
    __shared__ float red[2][128];
    const int tid = threadIdx.x;
    const int mt = blockIdx.x, sc = blockIdx.y, b = blockIdx.z;
    const int row0 = b * 512 + sc * 128;
    const int col0 = mt * 128;
    const int lane = tid & 63;
    const int wave = tid >> 6;
    const int wrow = wave >> 1;
    const int wr = wrow * 64, wc = (wave & 1) * 64;
    const int l15 = lane & 15, lk = (lane >> 4) * 8;
    const int srow = tid >> 1;
    const int sh = (tid & 1) * 16;

    const unsigned short* Ag = cat + (size_t)(row0 + srow) * 832 + sh;
    const unsigned short* Bg = Wmax + (size_t)(col0 + srow) * 832 + sh;

    f32x4 acc[4][4] = {};
    float4 av0 = *(const float4*)Ag;
    float4 av1 = *(const float4*)(Ag + 8);
    float4 bv0 = *(const float4*)Bg;
    float4 bv1 = *(const float4*)(Bg + 8);

    for (int kk = 0; kk < 26; ++kk) {
        __syncthreads();
        *(float4*)&As[srow * 40 + sh] = av0;
        *(float4*)&As[srow * 40 + sh + 8] = av1;
        *(float4*)&Bs[srow * 40 + sh] = bv0;
        *(float4*)&Bs[srow * 40 + sh + 8] = bv1;
        __syncthreads();
        if (kk < 25) {
            av0 = *(const float4*)(Ag + (kk + 1) * 32);
            av1 = *(const float4*)(Ag + (kk + 1) * 32 + 8);
            bv0 = *(const float4*)(Bg + (kk + 1) * 32);
            bv1 = *(const float4*)(Bg + (kk + 1) * 32 + 8);
        }
        s16x8 af[4], bf[4];
#pragma unroll
        for (int f = 0; f < 4; ++f) {
            af[f] = *(const s16x8*)&As[(wr + f * 16 + l15) * 40 + lk];
            bf[f] = *(const s16x8*)&Bs[(wc + f * 16 + l15) * 40 + lk];
        }
#pragma unroll
        for (int i = 0; i < 4; ++i)
#pragma unroll
            for (int j = 0; j < 4; ++j)
                acc[i][j] = __builtin_amdgcn_mfma_f32_16x16x32_bf16(af[i], bf[j], acc[i][j], 0, 0, 0);
    }

#pragma unroll
    for (int j = 0; j < 4; ++j) {
        float m = -1e30f;
#pragma unroll
        for (int i = 0; i < 4; ++i)
#pragma unroll
            for (int r = 0; r < 4; ++r) m = fmaxf(m, acc[i][j][r]);
        m = fmaxf(m, __shfl_xor(m, 16));
        m = fmaxf(m, __shfl_xor(m, 32));
        if (lane < 16) red[wrow][wc + j * 16 + lane] = m;
    }
    __syncthreads();
    if (tid < 128) {
        float v = fmaxf(red[0][tid], red[1][tid]);
        part_max[((size_t)(b * 4 + sc)) * kM + col0 + tid] = v;
    }
}

// K4: combine partial maxes, tanh(.+max_b), doc layer, log_softmax. (unchanged)
__global__ __launch_bounds__(256) void final_kernel(
    const float* __restrict__ part_max, const float* __restrict__ max_b,
    const float* __restrict__ doc_w, const float* __restrict__ doc_b,
    float* __restrict__ out)
{
    const int b = blockIdx.x;
    const int t = threadIdx.x;
    __shared__ float ym[kM];
    __shared__ float red[160];
    __shared__ float logits[kC];

    for (int m = t; m < kM; m += 256) {
        float v = -1e30f;
        for (int ch = 0; ch < 4; ++ch)
            v = fmaxf(v, part_max[((size_t)(b * 4 + ch)) * kM + m]);
        ym[m] = fast_tanh(v + max_b[m]);
    }
    __syncthreads();
    if (t < 160) {
        int c = t >> 3, kg = t & 7;
        float s = 0.f;
        const float* wr = doc_w + c * kM + kg * 64;
        const float* yr = ym + kg * 64;
        for (int k = 0; k < 64; ++k) s += yr[k] * wr[k];
        red[t] = s;
    }
    __syncthreads();
    if (t < kC) {
        float s = doc_b[t];
        for (int kg = 0; kg < 8; ++kg) s += red[t * 8 + kg];
        logits[t] = s;
    }
    __syncthreads();
    if (t == 0) {
        float mx = logits[0];
        for (int c = 1; c < kC; ++c) mx = fmaxf(mx, logits[c]);
        float se = 0.f;
        for (int c = 0; c < kC; ++c) se += __expf(logits[c] - mx);
        float lse = mx + __logf(se);
        for (int c = 0; c < kC; ++c) out[b * kC + c] = logits[c] - lse;
    }
}

extern "C" void kernel_launch(void* const* d_in, const int* in_sizes, int n_in,
                              void* d_out, int out_size, void* d_ws, size_t ws_size,
                              hipStream_t stream) {
    const int* inp = (const int*)d_in[0];
    const float* emb_table = (const float*)d_in[1];
    const float* c_l0 = (const float*)d_in[2];
    const float* c_r0 = (const float*)d_in[3];
    const float* W_l_w = (const float*)d_in[4];
    const float* W_l_b = (const float*)d_in[5];
    const float* W_r_w = (const float*)d_in[6];
    const float* W_r_b = (const float*)d_in[7];
    const float* W_sl_w = (const float*)d_in[8];
    const float* W_sl_b = (const float*)d_in[9];
    const float* W_sr_w = (const float*)d_in[10];
    const float* W_sr_b = (const float*)d_in[11];
    const float* max_w = (const float*)d_in[12];
    const float* max_b = (const float*)d_in[13];
    const float* doc_w = (const float*)d_in[14];
    const float* doc_b = (const float*)d_in[15];
    float* out = (float*)d_out;

    // Workspace: 56,492,032 bytes total.
    char* w = (char*)d_ws;
    unsigned short* cat   = (unsigned short*)(w);                 // 32768*832*2 = 54,525,952
    unsigned short* Wmax  = (unsigned short*)(w + 54525952);      // 512*832*2   =    851,968
    unsigned short* Wproj = (unsigned short*)(w + 55377920);      // 512*320*2   =    327,680
    float* part_max       = (float*)(w + 55705600);               // 4*64*512*4  =    524,288
    unsigned short* Wscan = (unsigned short*)(w + 56229888);      // 2*256*256*2 =    262,144

    prepw_kernel<<<(512 * 832 + 255) / 256, 256, 0, stream>>>(
        max_w, W_sl_w, W_sr_w, W_l_w, W_r_w, Wmax, Wproj, Wscan);
    gather_kernel<<<kS * kB, 128, 0, stream>>>(inp, emb_table, cat);
    proj_mfma_kernel<<<dim3(256, 4), 256, 0, stream>>>(
        cat, Wproj, W_sl_b, W_sr_b);
    scan_mfma_kernel<<<8, 256, 0, stream>>>(
        c_l0, c_r0, W_l_b, W_r_b, Wscan, cat);
    maxlayer_mfma_kernel<<<dim3(4, 4, 64), 256, 0, stream>>>(cat, Wmax, part_max);
    final_kernel<<<kB, 256, 0, stream>>>(part_max, max_b, doc_w, doc_b, out);
}

// Round 6
// 629.540 us; speedup vs baseline: 1.7875x; 1.7875x over previous
//
#include <hip/hip_runtime.h>
#include <hip/hip_bf16.h>

// Problem dims
constexpr int kS = 512;
constexpr int kB = 64;
constexpr int kE = 300;
constexpr int kH = 256;
constexpr int kM = 512;
constexpr int kC = 20;

typedef short s16x8 __attribute__((ext_vector_type(8)));
typedef float f32x4 __attribute__((ext_vector_type(4)));
typedef unsigned short u16x4 __attribute__((ext_vector_type(4)));
typedef _Float16 f16x8 __attribute__((ext_vector_type(8)));

__device__ __forceinline__ float fast_tanh(float z) {
    z = fminf(15.f, fmaxf(-15.f, z));
    float e = __expf(2.f * z);
    return 1.f - 2.f / (e + 1.f);
}

__device__ __forceinline__ unsigned short f2bf(float f) {
    __hip_bfloat16 h = __float2bfloat16(f);
    return *(unsigned short*)&h;
}
__device__ __forceinline__ float bf2f(unsigned short u) {
    __hip_bfloat16 h = *(__hip_bfloat16*)&u;
    return __bfloat162float(h);
}
union F16U { _Float16 h; unsigned short u; };
__device__ __forceinline__ unsigned short f16bits(_Float16 h) { F16U x; x.h = h; return x.u; }

// ---------------------------------------------------------------------------
// Buffers:
//   E   [32768][320] bf16 : emb (300) + zero pad (20); row = b*512+s
//   XCL [512][64][256] bf16: proj pre-acts -> scan overwrites with c_ls (in place)
//   XCR [512][64][256] bf16: same for right scan
//   Wmax [512][832] bf16: cols [0,256)=max_w[:,0:256), [256,576)=max_w[:,256:556)+20z,
//                         [576,832)=max_w[:,556:812)
//   Wproj [512][320] bf16, Wscan [2][256][256] f16
// ---------------------------------------------------------------------------

__global__ __launch_bounds__(256) void prepw_kernel(
    const float* __restrict__ max_w,
    const float* __restrict__ wsl, const float* __restrict__ wsr,
    const float* __restrict__ wl, const float* __restrict__ wr,
    unsigned short* __restrict__ Wmax, unsigned short* __restrict__ Wproj,
    unsigned short* __restrict__ Wscan)
{
    int idx = blockIdx.x * 256 + threadIdx.x;
    if (idx < 512 * 832) {
        int r = idx / 832, c = idx - r * 832;
        float v;
        if (c < 556)      v = max_w[r * 812 + c];
        else if (c < 576) v = 0.f;
        else              v = max_w[r * 812 + (c - 20)];
        Wmax[idx] = f2bf(v);
    }
    if (idx < 512 * 320) {
        int r = idx / 320, c = idx - r * 320;
        float v = 0.f;
        if (c < 300) v = (r < 256) ? wsl[r * 300 + c] : wsr[(r - 256) * 300 + c];
        Wproj[idx] = f2bf(v);
    }
    if (idx < 2 * 256 * 256) {
        int d = idx >> 16, rc = idx & 65535;
        float v = (d ? wr : wl)[rc];
        Wscan[idx] = f16bits((_Float16)v);
    }
}

// gather: emb rows -> E[b*512+s][0..300), zeros [300,320)
__global__ __launch_bounds__(128) void gather_kernel(
    const int* __restrict__ inp, const float* __restrict__ emb_table,
    unsigned short* __restrict__ E)
{
    const int row = blockIdx.x;          // b*512 + s
    const int b = row >> 9, s = row & 511;
    const int t = threadIdx.x;
    unsigned short* dst = E + (size_t)row * 320;
    const int v = inp[s * kB + b];
    const float* src = emb_table + (size_t)v * kE;
    if (t < 75) {
        float4 f = *(const float4*)&src[t * 4];
        u16x4 o = { f2bf(f.x), f2bf(f.y), f2bf(f.z), f2bf(f.w) };
        *(u16x4*)&dst[t * 4] = o;
    } else if (t < 80) {
        u16x4 z = { 0, 0, 0, 0 };
        *(u16x4*)&dst[300 + (t - 75) * 4] = z;
    }
}

// proj GEMM: A = E (K=320), B = Wproj. Epilogue -> XCL/XCR [s][b][256] bf16.
__global__ __launch_bounds__(256) void proj_mfma_kernel(
    const unsigned short* __restrict__ E,
    const unsigned short* __restrict__ Wproj,
    const float* __restrict__ b_sl, const float* __restrict__ b_sr,
    unsigned short* __restrict__ XCL, unsigned short* __restrict__ XCR)
{
    __shared__ unsigned short As[128 * 40];
    __shared__ unsigned short Bs[128 * 40];
    const int tid = threadIdx.x;
    const int row0 = blockIdx.x * 128;
    const int col0 = blockIdx.y * 128;
    const int lane = tid & 63;
    const int wave = tid >> 6;
    const int wr = (wave >> 1) * 64, wc = (wave & 1) * 64;
    const int l15 = lane & 15, lk = (lane >> 4) * 8;
    const int srow = tid >> 1;
    const int sh = (tid & 1) * 16;

    const unsigned short* Ag = E + (size_t)(row0 + srow) * 320 + sh;
    const unsigned short* Bg = Wproj + (size_t)(col0 + srow) * 320 + sh;

    f32x4 acc[4][4] = {};
    float4 av0 = *(const float4*)Ag;
    float4 av1 = *(const float4*)(Ag + 8);
    float4 bv0 = *(const float4*)Bg;
    float4 bv1 = *(const float4*)(Bg + 8);

    for (int kk = 0; kk < 10; ++kk) {
        __syncthreads();
        *(float4*)&As[srow * 40 + sh] = av0;
        *(float4*)&As[srow * 40 + sh + 8] = av1;
        *(float4*)&Bs[srow * 40 + sh] = bv0;
        *(float4*)&Bs[srow * 40 + sh + 8] = bv1;
        __syncthreads();
        if (kk < 9) {
            av0 = *(const float4*)(Ag + (kk + 1) * 32);
            av1 = *(const float4*)(Ag + (kk + 1) * 32 + 8);
            bv0 = *(const float4*)(Bg + (kk + 1) * 32);
            bv1 = *(const float4*)(Bg + (kk + 1) * 32 + 8);
        }
        s16x8 af[4], bf[4];
#pragma unroll
        for (int f = 0; f < 4; ++f) {
            af[f] = *(const s16x8*)&As[(wr + f * 16 + l15) * 40 + lk];
            bf[f] = *(const s16x8*)&Bs[(wc + f * 16 + l15) * 40 + lk];
        }
#pragma unroll
        for (int i = 0; i < 4; ++i)
#pragma unroll
            for (int j = 0; j < 4; ++j)
                acc[i][j] = __builtin_amdgcn_mfma_f32_16x16x32_bf16(af[i], bf[j], acc[i][j], 0, 0, 0);
    }

    const int rbase = row0 + wr + (lane >> 4) * 4;
#pragma unroll
    for (int j = 0; j < 4; ++j) {
        const int col = col0 + wc + j * 16 + l15;           // h' in [0,512)
        const float bias = (col < kH) ? b_sl[col] : b_sr[col - kH];
        unsigned short* X = (col < kH) ? XCL : XCR;
        const int ccol = col & 255;
#pragma unroll
        for (int i = 0; i < 4; ++i) {
#pragma unroll
            for (int r = 0; r < 4; ++r) {
                const int row = rbase + i * 16 + r;         // b*512+s
                const int s = row & 511, b = row >> 9;
                X[((size_t)s * 64 + b) * 256 + ccol] = f2bf(acc[i][j][r] + bias);
            }
        }
    }
}

// ---------------------------------------------------------------------------
// MFMA scan, issue-optimized. 8 blocks = 2 dir x 4 batch-groups of 16.
// 512 threads (8 waves); wave owns 32 output cols (2 x 16-col tiles).
// Single-f16 recurrence (c stored bf16). x prefetch 2 steps direct to regs.
// c frags double-buffered in swizzled LDS; 1 barrier/step.
// ---------------------------------------------------------------------------
__global__ __launch_bounds__(512, 2) void scan_mfma_kernel(
    const float* __restrict__ c_l0, const float* __restrict__ c_r0,
    const float* __restrict__ b_l, const float* __restrict__ b_r,
    const unsigned short* __restrict__ Wscan,   // [2][256][256] f16
    unsigned short* __restrict__ XCL, unsigned short* __restrict__ XCR)
{
    __shared__ unsigned short cF[2][16 * 256];

    const int dir = blockIdx.x >> 2;
    const int bg  = blockIdx.x & 3;
    const int tid = threadIdx.x;
    const int lane = tid & 63;
    const int wave = tid >> 6;          // 0..7
    const int l15 = lane & 15;
    const int q4  = lane >> 4;          // 0..3
    const int lk  = q4 * 8;
    const int n0  = wave * 32;

    const float* bias = dir ? b_r : b_l;
    const float* c0v  = dir ? c_r0 : c_l0;
    const unsigned short* W = Wscan + (dir << 16);
    unsigned short* XC = dir ? XCR : XCL;

    // B-frags: W rows n0+j*16+l15, k = ks*32+lk
    f16x8 wf[2][8];
#pragma unroll
    for (int j = 0; j < 2; ++j)
#pragma unroll
        for (int ks = 0; ks < 8; ++ks)
            wf[j][ks] = *(const f16x8*)&W[(n0 + j * 16 + l15) * 256 + ks * 32 + lk];

    float biasv[2];
#pragma unroll
    for (int j = 0; j < 2; ++j) biasv[j] = bias[n0 + j * 16 + l15];

    // per-r global base (batch bg*16+q4*4+r, col n0+l15); step s adds s*16384
    unsigned short* xbase[4];
#pragma unroll
    for (int r = 0; r < 4; ++r)
        xbase[r] = XC + (size_t)(bg * 16 + q4 * 4 + r) * 256 + n0 + l15;

    // swizzled LDS offsets
    int ridx[8], widx[2][4];
#pragma unroll
    for (int ks = 0; ks < 8; ++ks)
        ridx[ks] = (l15 * 256 + ks * 32 + lk) ^ ((l15 & 7) << 3);
#pragma unroll
    for (int j = 0; j < 2; ++j)
#pragma unroll
        for (int r = 0; r < 4; ++r) {
            int row = q4 * 4 + r;
            widx[j][r] = (row * 256 + n0 + j * 16 + l15) ^ ((row & 7) << 3);
        }

    // init c0 into cF[0]
    if (tid < 256) {
        unsigned short hb = f16bits((_Float16)c0v[tid]);
        for (int row = 0; row < 16; ++row)
            cF[0][(row * 256 + tid) ^ ((row & 7) << 3)] = hb;
    }

    // prologue x loads: s(0), s(1)
    const int s0i = dir ? 511 : 0;
    const int s1i = dir ? 510 : 1;
    unsigned short xa[8], xb[8];
#pragma unroll
    for (int j = 0; j < 2; ++j)
#pragma unroll
        for (int r = 0; r < 4; ++r) {
            xa[j * 4 + r] = xbase[r][(size_t)s0i * 16384 + j * 16];
            xb[j * 4 + r] = xbase[r][(size_t)s1i * 16384 + j * 16];
        }
    __syncthreads();

    auto body = [&](int t, unsigned short (&xc)[8]) {
        const int st = dir ? (511 - t) : t;
        int sld = dir ? (st - 2) : (st + 2);
        sld = min(511, max(0, sld));
        const int p = t & 1;

        f32x4 acc[2];
#pragma unroll
        for (int j = 0; j < 2; ++j)
#pragma unroll
            for (int r = 0; r < 4; ++r)
                acc[j][r] = biasv[j] + bf2f(xc[j * 4 + r]);

        // prefetch x(t+2) into same slots (old values consumed above)
#pragma unroll
        for (int j = 0; j < 2; ++j)
#pragma unroll
            for (int r = 0; r < 4; ++r)
                xc[j * 4 + r] = xbase[r][(size_t)sld * 16384 + j * 16];

        f16x8 ah[8];
#pragma unroll
        for (int ks = 0; ks < 8; ++ks)
            ah[ks] = *(const f16x8*)&cF[p][ridx[ks]];
#pragma unroll
        for (int ks = 0; ks < 8; ++ks) {
            acc[0] = __builtin_amdgcn_mfma_f32_16x16x32_f16(ah[ks], wf[0][ks], acc[0], 0, 0, 0);
            acc[1] = __builtin_amdgcn_mfma_f32_16x16x32_f16(ah[ks], wf[1][ks], acc[1], 0, 0, 0);
        }

#pragma unroll
        for (int j = 0; j < 2; ++j)
#pragma unroll
            for (int r = 0; r < 4; ++r) {
                float c = fast_tanh(acc[j][r]);
                xbase[r][(size_t)st * 16384 + j * 16] = f2bf(c);   // in-place c
                cF[p ^ 1][widx[j][r]] = f16bits((_Float16)c);
            }
        __syncthreads();
    };

    for (int t = 0; t < kS; t += 2) {
        body(t, xa);
        body(t + 1, xb);
    }
}

// maxlayer GEMM: A staged from 3 sources (XCL | E | XCR), B = Wmax. K=832.
__global__ __launch_bounds__(256) void maxlayer_mfma_kernel(
    const unsigned short* __restrict__ XCL, const unsigned short* __restrict__ E,
    const unsigned short* __restrict__ XCR, const unsigned short* __restrict__ Wmax,
    float* __restrict__ part_max)
{
    __shared__ unsigned short As[128 * 40];
    __shared__ unsigned short Bs[128 * 40];
    __shared__ float red[2][128];
    const int tid = threadIdx.x;
    const int mt = blockIdx.x, sc = blockIdx.y, b = blockIdx.z;
    const int col0 = mt * 128;
    const int lane = tid & 63;
    const int wave = tid >> 6;
    const int wrow = wave >> 1;
    const int wr = wrow * 64, wc = (wave & 1) * 64;
    const int l15 = lane & 15, lk = (lane >> 4) * 8;
    const int srow = tid >> 1;
    const int sh = (tid & 1) * 16;

    const int s = sc * 128 + srow;
    const unsigned short* baseL = XCL + ((size_t)s * 64 + b) * 256 + sh;
    const unsigned short* baseE = E + (size_t)(b * 512 + s) * 320 + sh;
    const unsigned short* baseR = XCR + ((size_t)s * 64 + b) * 256 + sh;
    const unsigned short* Bg = Wmax + (size_t)(col0 + srow) * 832 + sh;

    auto aptr = [&](int kk) -> const unsigned short* {
        if (kk < 8)  return baseL + kk * 32;
        if (kk < 18) return baseE + (kk - 8) * 32;
        return baseR + (kk - 18) * 32;
    };

    f32x4 acc[4][4] = {};
    float4 av0 = *(const float4*)aptr(0);
    float4 av1 = *(const float4*)(aptr(0) + 8);
    float4 bv0 = *(const float4*)Bg;
    float4 bv1 = *(const float4*)(Bg + 8);

    for (int kk = 0; kk < 26; ++kk) {
        __syncthreads();
        *(float4*)&As[srow * 40 + sh] = av0;
        *(float4*)&As[srow * 40 + sh + 8] = av1;
        *(float4*)&Bs[srow * 40 + sh] = bv0;
        *(float4*)&Bs[srow * 40 + sh + 8] = bv1;
        __syncthreads();
        if (kk < 25) {
            const unsigned short* ap = aptr(kk + 1);
            av0 = *(const float4*)ap;
            av1 = *(const float4*)(ap + 8);
            bv0 = *(const float4*)(Bg + (kk + 1) * 32);
            bv1 = *(const float4*)(Bg + (kk + 1) * 32 + 8);
        }
        s16x8 af[4], bf[4];
#pragma unroll
        for (int f = 0; f < 4; ++f) {
            af[f] = *(const s16x8*)&As[(wr + f * 16 + l15) * 40 + lk];
            bf[f] = *(const s16x8*)&Bs[(wc + f * 16 + l15) * 40 + lk];
        }
#pragma unroll
        for (int i = 0; i < 4; ++i)
#pragma unroll
            for (int j = 0; j < 4; ++j)
                acc[i][j] = __builtin_amdgcn_mfma_f32_16x16x32_bf16(af[i], bf[j], acc[i][j], 0, 0, 0);
    }

#pragma unroll
    for (int j = 0; j < 4; ++j) {
        float m = -1e30f;
#pragma unroll
        for (int i = 0; i < 4; ++i)
#pragma unroll
            for (int r = 0; r < 4; ++r) m = fmaxf(m, acc[i][j][r]);
        m = fmaxf(m, __shfl_xor(m, 16));
        m = fmaxf(m, __shfl_xor(m, 32));
        if (lane < 16) red[wrow][wc + j * 16 + lane] = m;
    }
    __syncthreads();
    if (tid < 128) {
        float v = fmaxf(red[0][tid], red[1][tid]);
        part_max[((size_t)(b * 4 + sc)) * kM + col0 + tid] = v;
    }
}

// final: combine partial maxes, tanh(.+max_b), doc layer, log_softmax.
__global__ __launch_bounds__(256) void final_kernel(
    const float* __restrict__ part_max, const float* __restrict__ max_b,
    const float* __restrict__ doc_w, const float* __restrict__ doc_b,
    float* __restrict__ out)
{
    const int b = blockIdx.x;
    const int t = threadIdx.x;
    __shared__ float ym[kM];
    __shared__ float red[160];
    __shared__ float logits[kC];

    for (int m = t; m < kM; m += 256) {
        float v = -1e30f;
        for (int ch = 0; ch < 4; ++ch)
            v = fmaxf(v, part_max[((size_t)(b * 4 + ch)) * kM + m]);
        ym[m] = fast_tanh(v + max_b[m]);
    }
    __syncthreads();
    if (t < 160) {
        int c = t >> 3, kg = t & 7;
        float s = 0.f;
        const float* wr = doc_w + c * kM + kg * 64;
        const float* yr = ym + kg * 64;
        for (int k = 0; k < 64; ++k) s += yr[k] * wr[k];
        red[t] = s;
    }
    __syncthreads();
    if (t < kC) {
        float s = doc_b[t];
        for (int kg = 0; kg < 8; ++kg) s += red[t * 8 + kg];
        logits[t] = s;
    }
    __syncthreads();
    if (t == 0) {
        float mx = logits[0];
        for (int c = 1; c < kC; ++c) mx = fmaxf(mx, logits[c]);
        float se = 0.f;
        for (int c = 0; c < kC; ++c) se += __expf(logits[c] - mx);
        float lse = mx + __logf(se);
        for (int c = 0; c < kC; ++c) out[b * kC + c] = logits[c] - lse;
    }
}

extern "C" void kernel_launch(void* const* d_in, const int* in_sizes, int n_in,
                              void* d_out, int out_size, void* d_ws, size_t ws_size,
                              hipStream_t stream) {
    const int* inp = (const int*)d_in[0];
    const float* emb_table = (const float*)d_in[1];
    const float* c_l0 = (const float*)d_in[2];
    const float* c_r0 = (const float*)d_in[3];
    const float* W_l_w = (const float*)d_in[4];
    const float* W_l_b = (const float*)d_in[5];
    const float* W_r_w = (const float*)d_in[6];
    const float* W_r_b = (const float*)d_in[7];
    const float* W_sl_w = (const float*)d_in[8];
    const float* W_sl_b = (const float*)d_in[9];
    const float* W_sr_w = (const float*)d_in[10];
    const float* W_sr_b = (const float*)d_in[11];
    const float* max_w = (const float*)d_in[12];
    const float* max_b = (const float*)d_in[13];
    const float* doc_w = (const float*)d_in[14];
    const float* doc_b = (const float*)d_in[15];
    float* out = (float*)d_out;

    // Workspace: 56,492,032 bytes total (same footprint as passing R5).
    char* w = (char*)d_ws;
    unsigned short* E     = (unsigned short*)(w);                 // 32768*320*2 = 20,971,520
    unsigned short* XCL   = (unsigned short*)(w + 20971520);      // 512*64*256*2 = 16,777,216
    unsigned short* XCR   = (unsigned short*)(w + 37748736);      // 16,777,216
    unsigned short* Wmax  = (unsigned short*)(w + 54525952);      // 851,968
    unsigned short* Wproj = (unsigned short*)(w + 55377920);      // 327,680
    float* part_max       = (float*)(w + 55705600);               // 524,288
    unsigned short* Wscan = (unsigned short*)(w + 56229888);      // 262,144

    prepw_kernel<<<(512 * 832 + 255) / 256, 256, 0, stream>>>(
        max_w, W_sl_w, W_sr_w, W_l_w, W_r_w, Wmax, Wproj, Wscan);
    gather_kernel<<<kS * kB, 128, 0, stream>>>(inp, emb_table, E);
    proj_mfma_kernel<<<dim3(256, 4), 256, 0, stream>>>(
        E, Wproj, W_sl_b, W_sr_b, XCL, XCR);
    scan_mfma_kernel<<<8, 512, 0, stream>>>(
        c_l0, c_r0, W_l_b, W_r_b, Wscan, XCL, XCR);
    maxlayer_mfma_kernel<<<dim3(4, 4, 64), 256, 0, stream>>>(
        XCL, E, XCR, Wmax, part_max);
    final_kernel<<<kB, 256, 0, stream>>>(part_max, max_b, doc_w, doc_b, out);
}